// Round 4
// baseline (106.712 us; speedup 1.0000x reference)
//
#include <hip/hip_runtime.h>
#include <hip/hip_bf16.h>
#include <stdint.h>

typedef __attribute__((ext_vector_type(8))) __bf16 bf16x8;
typedef __attribute__((ext_vector_type(16))) float floatx16;

#if __has_builtin(__builtin_amdgcn_exp2f)
#define EXP2F(x) __builtin_amdgcn_exp2f(x)
#else
#define EXP2F(x) exp2f(x)
#endif

#define GAS __attribute__((address_space(1)))
#define LAS __attribute__((address_space(3)))

// sqrt(2*log2(e)): baked into normalized rows so dot = 2*log2(e)*cos and
// sim = exp2(dot) = exp(cos/0.5) with zero epilogue multiplies.
#define SCALE_SQRT 1.69864359f

// ---------------- prep: int64-probe labels + normalize -----------------------
__global__ __launch_bounds__(256) void k_prep(const float* __restrict__ x,
                                              const int* __restrict__ raw,
                                              ushort* __restrict__ xb,
                                              unsigned char* __restrict__ lab8,
                                              int N) {
  const int row = (blockIdx.x * 256 + threadIdx.x) >> 6;  // one wave per row
  const int lane = threadIdx.x & 63;
  if (row >= N) return;
  // parallel int64 detection: odd words all zero => labels are int64
  const int probe = raw[2 * lane + 1];
  const bool is64 = (__ballot(probe != 0) == 0ull);
  const float2 v = ((const float2*)(x + (size_t)row * 128))[lane];
  float ss = v.x * v.x + v.y * v.y;
#pragma unroll
  for (int m = 1; m < 64; m <<= 1) ss += __shfl_xor(ss, m, 64);
  const float rn = SCALE_SQRT / fmaxf(sqrtf(ss), 1e-12f);
  __hip_bfloat162 o;
  o.x = __float2bfloat16(v.x * rn);
  o.y = __float2bfloat16(v.y * rn);
  ((__hip_bfloat162*)xb)[row * 64 + lane] = o;
  // labels are 0..63 -> byte-pack (lossless)
  if (lane == 0) lab8[row] = (unsigned char)(is64 ? raw[2 * row] : raw[row]);
}

// ---------------- main: persistent-block symmetric upper-triangle ------------
// 512 persistent blocks (2/CU), each walks 4-5 contiguous u-major pairs (s,u),
// u>=s, of 128x128 blocks (2080 total). Cross-pair pipeline (T3-minimum):
//   iter k: [colflush k-1] [A+label loads] [stage B(k+1) -> buf^1]
//           [MFMA from buf, epilogue, cb writes] [rowflush stores]
//           [s_waitcnt vmcnt(16) lgkmcnt(0); s_barrier]
// Counted vmcnt leaves the 16 rowflush stores in flight; drains the 8
// stage ops so next iter's ds_reads are safe. One barrier per pair; stage
// latency hidden under compute. Col partials ride the mandatory barrier via
// double-buffered cb scratch. Row sums of pair (s,u) -> plane u rows of strip
// s; col sums -> plane s rows of strip u; unique writer per (plane,row).
__global__ __launch_bounds__(256, 2) void k_sim(const ushort* __restrict__ xb,
                                                const unsigned char* __restrict__ lab8,
                                                float2* __restrict__ ppart,
                                                int N) {
  __shared__ ushort ldsB[2][128 * 128];       // 2 x 32 KB, XOR-16 swizzled
  __shared__ float cb[2][4 * 2 * 2 * 2 * 32]; // 2 x 4 KB [wv][t][h][np][col]
  const int tid = threadIdx.x;
  const int lane = tid & 63;
  const int wv = tid >> 6;
  const int l31 = lane & 31, g2 = lane >> 5;
  const int l15 = lane & 15, g4 = lane >> 4;

  // chunk: blocks 0..31 take 5 pairs, 32..511 take 4  (2080 = 32*5 + 480*4)
  const int b = blockIdx.x;
  const int p0 = b * 4 + (b < 32 ? b : 32);
  const int np = (b < 32) ? 5 : 4;

  // decode p0 -> (s,u), u >= s, p = u*(u+1)/2 + s
  int u = (int)((sqrtf(8.0f * (float)p0 + 1.0f) - 1.0f) * 0.5f);
  while ((u + 1) * (u + 2) / 2 <= p0) ++u;
  while (u * (u + 1) / 2 > p0) --u;
  int s = p0 - u * (u + 1) / 2;

  auto stageB = [&](int buf, int uu) {
    const int jb = uu * 128;
#pragma unroll
    for (int it = 0; it < 8; ++it) {
      const int r0 = it * 16 + wv * 4;  // wave-uniform LDS row base
      const int lr = r0 + g4;
      const int kb = l15 ^ (lr & 15);
      const ushort* gp = xb + (size_t)(jb + lr) * 128 + kb * 8;
      __builtin_amdgcn_global_load_lds((GAS void*)gp, (LAS void*)&ldsB[buf][r0 * 128], 16, 0, 0);
    }
  };

  // prologue: stage pair p0's B, full drain, barrier
  stageB(0, u);
  asm volatile("s_waitcnt vmcnt(0)" ::: "memory");
  __builtin_amdgcn_s_barrier();
  __builtin_amdgcn_sched_barrier(0);

  int ps = 0, pu = 0;
  bool poffd = false;
  const uint* lab32 = (const uint*)lab8;

  for (int k = 0; k < np; ++k) {
    const int cur = k & 1;
    const int i0 = s * 128, jb0 = u * 128;
    const bool offd = (s != u);

    // ---- 1. col-flush of previous pair (reads cb[cur^1]; barrier-protected)
    if (k > 0 && poffd && tid < 128) {
      const int t = (tid >> 6) & 1, h = (tid >> 5) & 1, c5 = tid & 31;
      float n = 0.0f, p = 0.0f;
#pragma unroll
      for (int w = 0; w < 4; ++w) {
        n += cb[cur ^ 1][(((w * 2 + t) * 2 + h) * 2 + 0) * 32 + c5];
        p += cb[cur ^ 1][(((w * 2 + t) * 2 + h) * 2 + 1) * 32 + c5];
      }
      const int jrow = pu * 128 + t * 64 + h * 32 + c5;
      ppart[(size_t)ps * N + jrow] = float2{n, p};
    }

    // ---- 2. A fragments + labels for this pair (L2-hot) ----
    const int arow = i0 + wv * 32 + l31;
    bf16x8 af[8];
#pragma unroll
    for (int kt = 0; kt < 8; ++kt)
      af[kt] = *(const bf16x8*)(xb + (size_t)arow * 128 + (kt * 2 + g2) * 8);
    uint liw[4];
#pragma unroll
    for (int q = 0; q < 4; ++q)
      liw[q] = lab32[(i0 + wv * 32 + 8 * q + 4 * g2) >> 2];
    int lj[4];
#pragma unroll
    for (int t = 0; t < 2; ++t)
#pragma unroll
      for (int h = 0; h < 2; ++h) lj[t * 2 + h] = lab8[jb0 + t * 64 + h * 32 + l31];

    // ---- 3. stage next pair's B into the other buffer (hidden by compute)
    int ns = s + 1, nu = u;
    if (ns > nu) { ns = 0; ++nu; }
    if (k + 1 < np) stageB(cur ^ 1, nu);

    // ---- 4/5. MFMA + epilogue, per 64-col tile ----
    floatx16 vneg = (floatx16)(0.0f), vpos = (floatx16)(0.0f);
#pragma unroll
    for (int tile = 0; tile < 2; ++tile) {
      floatx16 acc0 = (floatx16)(0.0f), acc1 = (floatx16)(0.0f);
#pragma unroll
      for (int kt = 0; kt < 8; ++kt) {
        const int br0 = tile * 64 + l31;
        const int br1 = tile * 64 + 32 + l31;
        const bf16x8 b0 = *(const bf16x8*)&ldsB[cur][br0 * 128 + (((kt * 2 + g2) ^ (br0 & 15)) * 8)];
        const bf16x8 b1 = *(const bf16x8*)&ldsB[cur][br1 * 128 + (((kt * 2 + g2) ^ (br1 & 15)) * 8)];
        acc0 = __builtin_amdgcn_mfma_f32_32x32x16_bf16(af[kt], b0, acc0, 0, 0, 0);
        acc1 = __builtin_amdgcn_mfma_f32_32x32x16_bf16(af[kt], b1, acc1, 0, 0, 0);
      }
      if (offd) {
        float cn0 = 0.0f, cn1 = 0.0f, cp0 = 0.0f, cp1 = 0.0f;
#pragma unroll
        for (int r = 0; r < 16; ++r) {
          const int lr = (liw[r >> 2] >> ((r & 3) * 8)) & 255;
          const float e0 = EXP2F(acc0[r]);
          const float e1 = EXP2F(acc1[r]);
          const float s0 = (lr == lj[tile * 2 + 0]) ? e0 : 0.0f;
          const float s1 = (lr == lj[tile * 2 + 1]) ? e1 : 0.0f;
          vneg[r] += e0 + e1;
          vpos[r] += s0 + s1;
          cn0 += e0; cp0 += s0;
          cn1 += e1; cp1 += s1;
        }
        // column partials -> cb[cur] (read after the end-of-iter barrier)
        float a0 = cn0 + __shfl_xor(cn0, 32, 64);
        float b0 = cp0 + __shfl_xor(cp0, 32, 64);
        float a1 = cn1 + __shfl_xor(cn1, 32, 64);
        float b1 = cp1 + __shfl_xor(cp1, 32, 64);
        if (lane < 32) {
          cb[cur][(((wv * 2 + tile) * 2 + 0) * 2 + 0) * 32 + l31] = a0;
          cb[cur][(((wv * 2 + tile) * 2 + 0) * 2 + 1) * 32 + l31] = b0;
          cb[cur][(((wv * 2 + tile) * 2 + 1) * 2 + 0) * 32 + l31] = a1;
          cb[cur][(((wv * 2 + tile) * 2 + 1) * 2 + 1) * 32 + l31] = b1;
        }
      } else {
        const int jc0 = tile * 64 + l31;
        const int jc1 = tile * 64 + 32 + l31;
#pragma unroll
        for (int r = 0; r < 16; ++r) {
          const int lr = (liw[r >> 2] >> ((r & 3) * 8)) & 255;
          const int ir = wv * 32 + (r & 3) + 8 * (r >> 2) + 4 * g2;
          float e0 = EXP2F(acc0[r]);
          float e1 = EXP2F(acc1[r]);
          if (ir == jc0) e0 = 0.0f;  // exclude self-similarity exactly
          if (ir == jc1) e1 = 0.0f;
          vneg[r] += e0 + e1;
          vpos[r] += ((lr == lj[tile * 2 + 0]) ? e0 : 0.0f) +
                     ((lr == lj[tile * 2 + 1]) ? e1 : 0.0f);
        }
      }
    }

    // ---- 6. row flush: reduce over 32 col-lanes; one float2 store per row
#pragma unroll
    for (int r = 0; r < 16; ++r) {
      float n = vneg[r], p = vpos[r];
#pragma unroll
      for (int m = 1; m < 32; m <<= 1) {
        n += __shfl_xor(n, m, 64);
        p += __shfl_xor(p, m, 64);
      }
      if (l31 == 0) {
        const int row = i0 + wv * 32 + (r & 3) + 8 * (r >> 2) + 4 * g2;
        ppart[(size_t)u * N + row] = float2{n, p};
      }
    }

    // ---- 7. end-of-pair: counted drain (leaves rowflush stores in flight),
    // barrier makes buf[cur^1] staged + cb[cur] visible for next iteration.
    asm volatile("s_waitcnt vmcnt(16) lgkmcnt(0)" ::: "memory");
    __builtin_amdgcn_s_barrier();
    __builtin_amdgcn_sched_barrier(0);

    ps = s; pu = u; poffd = offd;
    s = ns; u = nu;
  }

  // ---- final col-flush (last pair) ----
  __syncthreads();
  if (poffd && tid < 128) {
    const int last = (np - 1) & 1;
    const int t = (tid >> 6) & 1, h = (tid >> 5) & 1, c5 = tid & 31;
    float n = 0.0f, p = 0.0f;
#pragma unroll
    for (int w = 0; w < 4; ++w) {
      n += cb[last][(((w * 2 + t) * 2 + h) * 2 + 0) * 32 + c5];
      p += cb[last][(((w * 2 + t) * 2 + h) * 2 + 1) * 32 + c5];
    }
    const int jrow = pu * 128 + t * 64 + h * 32 + c5;
    ppart[(size_t)ps * N + jrow] = float2{n, p};
  }
}

// ---------------- finalize: parallel over 32 blocks, 1 row/thread ------------
__global__ __launch_bounds__(256) void k_final(const float2* __restrict__ ppart,
                                               const unsigned char* __restrict__ lab8,
                                               double* __restrict__ partial,
                                               int N, int nstrip) {
  __shared__ int h[64];
  __shared__ double wsum[4];
  const int tid = threadIdx.x;
  if (tid < 64) h[tid] = 0;
  __syncthreads();
  for (int i = tid; i < N; i += 256) atomicAdd(&h[lab8[i] & 63], 1);
  __syncthreads();
  const int r = blockIdx.x * 256 + tid;
  double v = 0.0;
  if (r < N) {
    float n = 0.0f, p = 0.0f;
#pragma unroll 8
    for (int cc = 0; cc < nstrip; ++cc) {
      const float2 w = ppart[(size_t)cc * N + r];
      n += w.x;
      p += w.y;
    }
    const float cnt = (float)(h[lab8[r] & 63] - 1);
    v = (double)logf(n * cnt / p);
  }
#pragma unroll
  for (int m = 1; m < 64; m <<= 1) v += __shfl_xor(v, m, 64);
  if ((tid & 63) == 0) wsum[tid >> 6] = v;
  __syncthreads();
  if (tid == 0) partial[blockIdx.x] = wsum[0] + wsum[1] + wsum[2] + wsum[3];
}

__global__ __launch_bounds__(64) void k_write(const double* __restrict__ partial,
                                              float* __restrict__ out, int nfb, int N) {
  const int l = threadIdx.x;
  double v = 0.0;
  for (int i = l; i < nfb; i += 64) v += partial[i];
#pragma unroll
  for (int m = 1; m < 64; m <<= 1) v += __shfl_xor(v, m, 64);
  if (l == 0) out[0] = (float)(v / (double)N);
}

extern "C" void kernel_launch(void* const* d_in, const int* in_sizes, int n_in,
                              void* d_out, int out_size, void* d_ws, size_t ws_size,
                              hipStream_t stream) {
  const float* x = (const float*)d_in[0];
  const int* raw_label = (const int*)d_in[1];
  const int N = in_sizes[1];   // 8192
  const int nstrip = N / 128;  // 64
  char* ws = (char*)d_ws;
  ushort* xb = (ushort*)ws;                             // N*128 bf16 = 2 MB
  float2* ppart = (float2*)(ws + (size_t)N * 128 * 2);  // nstrip*N float2 = 4 MB
  unsigned char* lab8 = (unsigned char*)(ppart + (size_t)nstrip * N);  // N bytes
  double* partial = (double*)(lab8 + ((N + 7) & ~7));   // <=64 doubles
  float* out = (float*)d_out;

  const int nfb = (N + 255) / 256;  // 32 finalize blocks

  k_prep<<<dim3(N / 4), dim3(256), 0, stream>>>(x, raw_label, xb, lab8, N);
  k_sim<<<dim3(512), dim3(256), 0, stream>>>(xb, lab8, ppart, N);
  k_final<<<dim3(nfb), dim3(256), 0, stream>>>(ppart, lab8, partial, N, nstrip);
  k_write<<<dim3(1), dim3(64), 0, stream>>>(partial, out, nfb, N);
}